// Round 14
// baseline (45.628 us; speedup 1.0000x reference)
//
#include <hip/hip_runtime.h>

#define NPIX  65536
#define NG    512
#define NB    4
#define MAXD  362.03867196751236f
#define WRAD  24                  // Chebyshev window radius for term-2 fast path
#define WDIM  49                  // 2*WRAD+1
#define WCNT  2401                // WDIM*WDIM
#define SAFE_Q (23.0f - MAXD)     // group min <= this => window provably contains global min
#define NBLK_T1 128               // term-1: 8 rows per block (4 img x 32 row-groups)
#define NBLK    256               // total blocks = 1 per CU
// ws layout (floats):
#define PD_OFF  0                 // [0,128): term-1 per-block sum p*min_d
#define PP_OFF  128               // [128,256): term-1 per-block sum p
#define T2_OFF  256               // [256,2304): per-(b,g) min of p*(d-MAXD)
#define CNT_OFF 2304              // completion counter (memset to 0 each call)

__device__ __forceinline__ float wave_sum(float v){
  #pragma unroll
  for (int o = 32; o > 0; o >>= 1) v += __shfl_down(v, o, 64);
  return v;
}

__global__ __launch_bounds__(256) void k_main(const float* __restrict__ prob,
                                              const int* __restrict__ gt,
                                              float* __restrict__ ws,
                                              float* __restrict__ out){
  const int tid = threadIdx.x;
  __shared__ float2 gsab[NG];      // term-1 staging (4 KB)
  __shared__ float red[8];
  __shared__ float t1sh[NB];
  __shared__ float redT2[4];
  __shared__ int   lastFlag;

  if (blockIdx.x < NBLK_T1){
    // ----- term 1: block = (b, 8-row group); thread = column -----
    const int b  = blockIdx.x >> 5;                 // 32 blocks per image
    const int hp = (blockIdx.x & 31) << 3;          // rows hp .. hp+7
    const float wf = (float)tid;

    const int2* gtp = ((const int2*)gt) + b*NG;
    #pragma unroll
    for (int s = 0; s < 2; ++s){
      const int g = tid + 256*s;
      const int2 q = gtp[g];
      gsab[g] = make_float2(-2.0f*(float)q.x, -2.0f*(float)q.y);
    }
    __syncthreads();

    float hf[8], m[8];
    #pragma unroll
    for (int r = 0; r < 8; ++r){ hf[r] = (float)(hp + r); m[r] = 3e38f; }

    #pragma unroll 4
    for (int k = 0; k < 256; ++k){
      const float2 q0 = gsab[2*k + 0];              // merged ds_read_b128
      const float2 q1 = gsab[2*k + 1];
      float sc0 = q0.x*q0.x; sc0 = fmaf(q0.y, q0.y, sc0) * 0.25f;  // gh^2+gw^2 exact
      float sc1 = q1.x*q1.x; sc1 = fmaf(q1.y, q1.y, sc1) * 0.25f;
      const float u0 = fmaf(q0.y, wf, sc0);         // sc - 2gw*w, exact int
      const float u1 = fmaf(q1.y, wf, sc1);
      #pragma unroll
      for (int r = 0; r < 8; ++r){
        const float t0 = fmaf(q0.x, hf[r], u0);     // d2 - (h^2+w^2), exact int
        const float t1 = fmaf(q1.x, hf[r], u1);
        m[r] = fminf(fminf(m[r], t0), t1);          // v_min3
      }
    }

    float spd = 0.0f, sp = 0.0f;
    const float w2 = (float)(tid*tid);
    #pragma unroll
    for (int r = 0; r < 8; ++r){
      const float d = __builtin_amdgcn_sqrtf(m[r] + fmaf(hf[r], hf[r], w2));
      const float p = prob[b*NPIX + (hp + r)*256 + tid];   // coalesced
      spd = fmaf(p, d, spd);
      sp += p;
    }

    spd = wave_sum(spd);
    sp  = wave_sum(sp);
    const int wid = tid >> 6, lane = tid & 63;
    if (lane == 0){ red[wid] = spd; red[4+wid] = sp; }
    __syncthreads();
    if (tid == 0){
      ws[PD_OFF + blockIdx.x] = (red[0]+red[1]) + (red[2]+red[3]);
      ws[PP_OFF + blockIdx.x] = (red[4]+red[5]) + (red[6]+red[7]);
    }
  } else {
    // ----- term 2: 16 points per block, one point per 16-lane group -----
    const int j2   = blockIdx.x - NBLK_T1;          // 0..127
    const int grp  = tid >> 4;                      // 0..15
    const int l16  = tid & 15;
    const int idx  = j2*16 + grp;                   // b*NG + g
    const int b    = idx >> 9;
    const int gh   = gt[idx*2 + 0];                 // group-uniform (L1 broadcast)
    const int gw   = gt[idx*2 + 1];

    float qm = 3e38f;
    for (int i = l16; i < WCNT; i += 16){
      const int r  = i / WDIM;
      const int c  = i - r*WDIM;
      const int hh = gh - WRAD + r;
      const int ww = gw - WRAD + c;
      if ((unsigned)hh < 256u && (unsigned)ww < 256u){
        const float p  = prob[b*NPIX + hh*256 + ww];
        const int  dh  = r - WRAD, dw = c - WRAD;
        const float d  = __builtin_amdgcn_sqrtf((float)(dh*dh + dw*dw));
        qm = fminf(qm, fmaf(p, d, p * (-MAXD)));
      }
    }
    #pragma unroll
    for (int o = 8; o > 0; o >>= 1) qm = fminf(qm, __shfl_xor(qm, o, 64));

    if (qm > SAFE_Q){
      // exact fallback: group rescans the full image (practically never taken)
      const float ghf = (float)gh, gwf = (float)gw;
      float q2 = 3e38f;
      for (int i = l16; i < NPIX; i += 16){
        const int hh = i >> 8, ww = i & 255;
        const float dh = (float)hh - ghf, dw = (float)ww - gwf;
        const float d  = __builtin_amdgcn_sqrtf(fmaf(dh, dh, dw*dw));
        const float p  = prob[b*NPIX + i];
        q2 = fminf(q2, fmaf(p, d, p * (-MAXD)));
      }
      #pragma unroll
      for (int o = 8; o > 0; o >>= 1) q2 = fminf(q2, __shfl_xor(q2, o, 64));
      qm = q2;
    }
    if (l16 == 0) ws[T2_OFF + idx] = qm;
  }

  // ---------- last-block finish (deterministic; 256 atomics total) ----------
  __syncthreads();
  if (tid == 0){
    __threadfence();                                 // release partials
    const unsigned t = atomicAdd((unsigned*)(ws + CNT_OFF), 1u);
    lastFlag = (t == NBLK - 1u);
  }
  __syncthreads();
  if (lastFlag){
    __threadfence();                                 // acquire all partials
    const int w = tid >> 6, lane = tid & 63;

    // term-2 sum: 2048 values, 8 per thread, coalesced
    float s = 0.0f;
    #pragma unroll
    for (int k = 0; k < 8; ++k) s += ws[T2_OFF + tid*8 + k];
    s = wave_sum(s);
    if (lane == 0) redT2[w] = s;

    // term-1: wave w = image w; lanes 0-31 carry pd, lanes 32-63 carry pp
    float v = (lane < 32) ? ws[PD_OFF + w*32 + lane] : ws[PP_OFF + w*32 + (lane - 32)];
    #pragma unroll
    for (int o = 16; o > 0; o >>= 1) v += __shfl_down(v, o, 32);
    const float ppv = __shfl(v, 32, 64);             // pp total (from lane 32)
    if (lane == 0) t1sh[w] = v / (ppv + 1e-6f);
    __syncthreads();

    if (tid == 0){
      const float s2    = (redT2[0]+redT2[1]) + (redT2[2]+redT2[3]);
      const float term2 = MAXD + s2 * (1.0f/2048.0f);
      const float term1 = ((t1sh[0]+t1sh[1]) + (t1sh[2]+t1sh[3])) * 0.25f;
      out[0] = term1 + term2;
    }
  }
}

extern "C" void kernel_launch(void* const* d_in, const int* in_sizes, int n_in,
                              void* d_out, int out_size, void* d_ws, size_t ws_size,
                              hipStream_t stream) {
  const float* prob = (const float*)d_in[0];
  const int*   gt   = (const int*)d_in[1];
  float* out = (float*)d_out;
  float* ws  = (float*)d_ws;

  hipMemsetAsync(ws + CNT_OFF, 0, 4, stream);        // reset completion counter
  hipLaunchKernelGGL(k_main, dim3(NBLK), dim3(256), 0, stream, prob, gt, ws, out);
}

// Round 15
// 27.922 us; speedup vs baseline: 1.6341x; 1.6341x over previous
//
#include <hip/hip_runtime.h>

#define NPIX  65536
#define NG    512
#define NB    4
#define MAXD  362.03867196751236f
#define WRAD  16                  // Chebyshev window radius for term-2 fast path
#define WDIM  33                  // 2*WRAD+1
#define WCNT  1089                // WDIM*WDIM
#define SAFE_Q (15.0f - MAXD)     // window min <= this => provably global (outside box: d > WRAD)
#define NBLK_T1 128               // term-1: 8 rows per block (4 img x 32 row-groups)
#define NBLK_T2 (NB*NG)           // 2048
#define NBLK_MAIN (NBLK_T1 + NBLK_T2)

// ws layout (floats):
//   [0,   128) : term-1 per-block partial sum of p*min_d   (img = blk>>5)
//   [512, 640) : term-1 per-block partial sum of p
//   [1024,3072): per-(b,g) min of p*(d - MAXD)

__device__ __forceinline__ float wave_sum(float v){
  #pragma unroll
  for (int o = 32; o > 0; o >>= 1) v += __shfl_down(v, o, 64);
  return v;
}
__device__ __forceinline__ float wave_min(float v){
  #pragma unroll
  for (int o = 32; o > 0; o >>= 1) v = fminf(v, __shfl_down(v, o, 64));
  return v;
}

// ---------- main: term-1 (blocks 0..127) + term-2 windows (blocks 128..2175) ----------
__global__ __launch_bounds__(256) void k_main(const float* __restrict__ prob,
                                              const int* __restrict__ gt,
                                              float* __restrict__ wsout){
  const int tid = threadIdx.x;

  if (blockIdx.x < NBLK_T1){
    // ----- term 1: block = (b, 8-row group); thread = column -----
    // g-constants in LDS; REGISTER DOUBLE-BUFFER of 8-g batches so the next
    // batch's ds_reads are in flight while the current batch computes
    // (~240cy VALU covers ~120cy LDS latency even at 1 wave/SIMD).
    __shared__ float2 gsab[NG];
    __shared__ float red[8];
    const int b  = blockIdx.x >> 5;                 // 32 blocks per image
    const int hp = (blockIdx.x & 31) << 3;          // rows hp .. hp+7
    const float wf = (float)tid;

    const int2* gtp = ((const int2*)gt) + b*NG;
    #pragma unroll
    for (int s = 0; s < 2; ++s){
      const int g = tid + 256*s;
      const int2 q = gtp[g];
      gsab[g] = make_float2(-2.0f*(float)q.x, -2.0f*(float)q.y);
    }
    __syncthreads();

    float hf[8], m[8];
    #pragma unroll
    for (int r = 0; r < 8; ++r){ hf[r] = (float)(hp + r); m[r] = 3e38f; }

    float2 cur[8], nxt[8];
    #pragma unroll
    for (int j = 0; j < 8; ++j) cur[j] = gsab[j];

    #pragma unroll 1
    for (int kb = 0; kb < 64; ++kb){
      const int nb = (kb + 1) & 63;                 // wraps: last iter reloads batch 0 (unused)
      #pragma unroll
      for (int j = 0; j < 8; ++j) nxt[j] = gsab[nb*8 + j];   // issued before compute

      #pragma unroll
      for (int j = 0; j < 4; ++j){
        const float2 q0 = cur[2*j + 0];
        const float2 q1 = cur[2*j + 1];
        const float sc0 = fmaf(q0.y, q0.y, q0.x*q0.x) * 0.25f;  // gh^2+gw^2, exact
        const float sc1 = fmaf(q1.y, q1.y, q1.x*q1.x) * 0.25f;
        const float u0  = fmaf(q0.y, wf, sc0);      // sc - 2gw*w, exact int
        const float u1  = fmaf(q1.y, wf, sc1);
        #pragma unroll
        for (int r = 0; r < 8; ++r){
          const float t0 = fmaf(q0.x, hf[r], u0);   // d2 - (h^2+w^2), exact int
          const float t1 = fmaf(q1.x, hf[r], u1);
          m[r] = fminf(fminf(m[r], t0), t1);        // v_min3
        }
      }
      #pragma unroll
      for (int j = 0; j < 8; ++j) cur[j] = nxt[j];
    }

    float spd = 0.0f, sp = 0.0f;
    const float w2 = (float)(tid*tid);
    #pragma unroll
    for (int r = 0; r < 8; ++r){
      const float d = __builtin_amdgcn_sqrtf(m[r] + fmaf(hf[r], hf[r], w2));
      const float p = prob[b*NPIX + (hp + r)*256 + tid];   // coalesced
      spd = fmaf(p, d, spd);
      sp += p;
    }

    spd = wave_sum(spd);
    sp  = wave_sum(sp);
    const int wid = tid >> 6, lane = tid & 63;
    if (lane == 0){ red[wid] = spd; red[4+wid] = sp; }
    __syncthreads();
    if (tid == 0){
      wsout[blockIdx.x]       = (red[0]+red[1]) + (red[2]+red[3]);
      wsout[512 + blockIdx.x] = (red[4]+red[5]) + (red[6]+red[7]);
    }
  } else {
    // ----- term 2: one (b,g) per block; window + exact in-block fallback -----
    __shared__ float red[8];
    const int idx = blockIdx.x - NBLK_T1;           // b*NG + g
    const int b   = idx >> 9;
    const int gh  = gt[idx*2 + 0];
    const int gw  = gt[idx*2 + 1];

    float qm = 3e38f;
    for (int i = tid; i < WCNT; i += 256){
      const int r  = i / WDIM;
      const int c  = i - r*WDIM;
      const int hh = gh - WRAD + r;
      const int ww = gw - WRAD + c;
      if ((unsigned)hh < 256u && (unsigned)ww < 256u){
        const float p  = prob[b*NPIX + hh*256 + ww];
        const int  dh  = r - WRAD, dw = c - WRAD;
        const float d  = __builtin_amdgcn_sqrtf((float)(dh*dh + dw*dw));
        qm = fminf(qm, fmaf(p, d, p * (-MAXD)));
      }
    }
    qm = wave_min(qm);
    const int wid = tid >> 6, lane = tid & 63;
    if (lane == 0) red[wid] = qm;
    __syncthreads();
    float qf = fminf(fminf(red[0], red[1]), fminf(red[2], red[3]));

    if (qf > SAFE_Q){
      // exact fallback: full-image rescan (block-uniform; rare, keeps kernel exact)
      const float ghf = (float)gh, gwf = (float)gw;
      const float aa  = -2.0f*ghf;
      const float wf  = (float)tid;
      const float bc  = fmaf(-2.0f*gwf, wf, fmaf(ghf, ghf, gwf*gwf));
      const float wsq = wf*wf;
      float q2 = 3e38f;
      const float* pr = prob + b*NPIX + tid;
      #pragma unroll 4
      for (int i = 0; i < 256; ++i){
        const float p   = pr[i*256];
        const float hfi = (float)i;
        const float d2v = fmaf(aa, hfi, fmaf(hfi, hfi, wsq) + bc);
        const float d   = __builtin_amdgcn_sqrtf(d2v);
        q2 = fminf(q2, fmaf(p, d, p * (-MAXD)));
      }
      q2 = wave_min(q2);
      __syncthreads();
      if (lane == 0) red[wid] = q2;
      __syncthreads();
      qf = fminf(fminf(red[0], red[1]), fminf(red[2], red[3]));
    }
    if (tid == 0) wsout[1024 + idx] = qf;
  }
}

// ---------- finish: fully parallel deterministic reduction ----------
__global__ __launch_bounds__(256) void k_finish(const float* __restrict__ ws,
                                                float* __restrict__ out){
  const int tid  = threadIdx.x;
  const int w    = tid >> 6;      // wave id == image id for term-1 part
  const int lane = tid & 63;
  __shared__ float redT2[4];
  __shared__ float t1sh[NB];

  // term-2 sum: 2048 values, 8 per thread, coalesced
  float s = 0.0f;
  #pragma unroll
  for (int j = 0; j < 8; ++j) s += ws[1024 + tid*8 + j];
  s = wave_sum(s);
  if (lane == 0) redT2[w] = s;

  // term-1: wave w = image w; lanes 0-31 carry pd partials, 32-63 carry pp
  float v = (lane < 32) ? ws[w*32 + lane] : ws[512 + w*32 + (lane - 32)];
  #pragma unroll
  for (int o = 16; o > 0; o >>= 1) v += __shfl_down(v, o, 32);
  const float ppv = __shfl(v, 32, 64);              // pp total (from lane 32)
  if (lane == 0) t1sh[w] = v / (ppv + 1e-6f);
  __syncthreads();

  if (tid == 0){
    const float s2    = (redT2[0]+redT2[1]) + (redT2[2]+redT2[3]);
    const float term2 = MAXD + s2 * (1.0f/2048.0f);
    const float term1 = ((t1sh[0]+t1sh[1]) + (t1sh[2]+t1sh[3])) * 0.25f;
    out[0] = term1 + term2;
  }
}

extern "C" void kernel_launch(void* const* d_in, const int* in_sizes, int n_in,
                              void* d_out, int out_size, void* d_ws, size_t ws_size,
                              hipStream_t stream) {
  const float* prob = (const float*)d_in[0];
  const int*   gt   = (const int*)d_in[1];
  float* out = (float*)d_out;
  float* ws  = (float*)d_ws;

  hipLaunchKernelGGL(k_main,   dim3(NBLK_MAIN), dim3(256), 0, stream, prob, gt, ws);
  hipLaunchKernelGGL(k_finish, dim3(1),         dim3(256), 0, stream, ws, out);
}